// Round 1
// baseline (1387.186 us; speedup 1.0000x reference)
//
#include <hip/hip_runtime.h>

#define T_  2
#define N_  10000
#define C_  64
#define H_  4
#define Co_ 64
#define E_  160000
#define HC_ 256          // H*Co
#define NEG_SLOPE 0.2f
#define LN_EPS 1e-5f

// monotone float <-> uint encoding for atomicMax on float
__device__ __forceinline__ unsigned enc_f32(float f) {
    unsigned b = __float_as_uint(f);
    return (b & 0x80000000u) ? ~b : (b | 0x80000000u);
}
__device__ __forceinline__ float dec_f32(unsigned u) {
    return __uint_as_float((u & 0x80000000u) ? (u & 0x7FFFFFFFu) : ~u);
}
__device__ __forceinline__ float lrelu(float v) {
    return v >= 0.f ? v : NEG_SLOPE * v;
}

// ---- Pass A: x_l = x@W_l + b_l, x_r = x@W_r + b_r  (one block per (t,n) row)
__global__ __launch_bounds__(256) void gemm_lr(
        const float* __restrict__ x, const float* __restrict__ Wl,
        const float* __restrict__ bl, const float* __restrict__ Wr,
        const float* __restrict__ br, float* __restrict__ xl,
        float* __restrict__ xr) {
    __shared__ float xs[C_];
    const int row = blockIdx.x;        // t*N + n
    const int j   = threadIdx.x;       // 0..255 output column
    if (j < C_) xs[j] = x[(size_t)row * C_ + j];
    __syncthreads();
    float accl = bl[j], accr = br[j];
    #pragma unroll 8
    for (int c = 0; c < C_; ++c) {
        const float xv = xs[c];
        accl = fmaf(xv, Wl[c * HC_ + j], accl);
        accr = fmaf(xv, Wr[c * HC_ + j], accr);
    }
    xl[(size_t)row * HC_ + j] = accl;
    xr[(size_t)row * HC_ + j] = accr;
}

// ---- Pass B: alpha[e,t,h] + segment max (one 64-lane wave per (e,t))
__global__ __launch_bounds__(256) void edge_alpha(
        const float* __restrict__ xl, const float* __restrict__ xr,
        const int* __restrict__ src, const int* __restrict__ dst,
        const float* __restrict__ att, float* __restrict__ alpha,
        unsigned* __restrict__ amax) {
    const int wid  = blockIdx.x * 4 + (threadIdx.x >> 6);  // p = e*T + t
    const int lane = threadIdx.x & 63;
    const int e = wid / T_, t = wid % T_;
    const int s = src[e], d = dst[e];
    const float4 xj = *(const float4*)&xl[((size_t)t * N_ + s) * HC_ + lane * 4];
    const float4 xi = *(const float4*)&xr[((size_t)t * N_ + d) * HC_ + lane * 4];
    const float4 av = *(const float4*)&att[lane * 4];
    float part = lrelu(xi.x + xj.x) * av.x + lrelu(xi.y + xj.y) * av.y +
                 lrelu(xi.z + xj.z) * av.z + lrelu(xi.w + xj.w) * av.w;
    // reduce across the 16 lanes of one head
    part += __shfl_xor(part, 1, 64);
    part += __shfl_xor(part, 2, 64);
    part += __shfl_xor(part, 4, 64);
    part += __shfl_xor(part, 8, 64);
    if ((lane & 15) == 0) {
        const int h = lane >> 4;
        alpha[(size_t)wid * H_ + h] = part;
        atomicMax(&amax[((size_t)t * N_ + d) * H_ + h], enc_f32(part));
    }
}

// ---- Pass C: a = exp(alpha - amax[dst]); denom += a  (in-place on alpha)
__global__ __launch_bounds__(256) void edge_exp(
        const int* __restrict__ dst, const unsigned* __restrict__ amax,
        float* __restrict__ alpha, float* __restrict__ denom) {
    const int tid = blockIdx.x * 256 + threadIdx.x;   // < E*T*H
    const int h = tid & 3;
    const int p = tid >> 2;
    const int t = p & 1;
    const int e = p >> 1;
    const int d = dst[e];
    const float m = dec_f32(amax[((size_t)t * N_ + d) * H_ + h]);
    const float a = __expf(alpha[tid] - m);
    alpha[tid] = a;
    unsafeAtomicAdd(&denom[((size_t)t * N_ + d) * H_ + h], a);
}

// ---- Pass D: agg[dst] += (a/denom) * x_l[src]  (one wave per (e,t))
__global__ __launch_bounds__(256) void edge_agg(
        const float* __restrict__ xl, const int* __restrict__ src,
        const int* __restrict__ dst, const float* __restrict__ a,
        const float* __restrict__ denom, float* __restrict__ agg) {
    const int wid  = blockIdx.x * 4 + (threadIdx.x >> 6);
    const int lane = threadIdx.x & 63;
    const int e = wid / T_, t = wid % T_;
    const int s = src[e], d = dst[e];
    const int h = lane >> 4;
    const float attn = a[(size_t)wid * H_ + h] /
                       denom[((size_t)t * N_ + d) * H_ + h];
    const float4 xj = *(const float4*)&xl[((size_t)t * N_ + s) * HC_ + lane * 4];
    float* out = &agg[((size_t)t * N_ + d) * HC_ + lane * 4];
    unsafeAtomicAdd(out + 0, attn * xj.x);
    unsafeAtomicAdd(out + 1, attn * xj.y);
    unsafeAtomicAdd(out + 2, attn * xj.z);
    unsafeAtomicAdd(out + 3, attn * xj.w);
}

// ---- Pass E: relu(agg+bias) @ W_proj + b_proj + x -> LN -> relu
__global__ __launch_bounds__(64) void epilogue(
        const float* __restrict__ agg, const float* __restrict__ bias,
        const float* __restrict__ Wp, const float* __restrict__ bp,
        const float* __restrict__ x, const float* __restrict__ gamma,
        const float* __restrict__ beta, float* __restrict__ out) {
    __shared__ float sh[HC_];
    const int row = blockIdx.x;      // t*N + n
    const int o   = threadIdx.x;     // 0..63
    #pragma unroll
    for (int k = o; k < HC_; k += 64)
        sh[k] = fmaxf(agg[(size_t)row * HC_ + k] + bias[k], 0.f);
    __syncthreads();
    float acc = bp[o] + x[(size_t)row * C_ + o];
    #pragma unroll 8
    for (int k = 0; k < HC_; ++k)
        acc = fmaf(sh[k], Wp[k * Co_ + o], acc);
    // LayerNorm across the 64-lane wave
    float s1 = acc;
    #pragma unroll
    for (int off = 1; off < 64; off <<= 1) s1 += __shfl_xor(s1, off, 64);
    const float mu = s1 * (1.f / 64.f);
    const float dv = acc - mu;
    float s2 = dv * dv;
    #pragma unroll
    for (int off = 1; off < 64; off <<= 1) s2 += __shfl_xor(s2, off, 64);
    const float var = s2 * (1.f / 64.f);
    const float y = dv * rsqrtf(var + LN_EPS) * gamma[o] + beta[o];
    out[(size_t)row * C_ + o] = fmaxf(y, 0.f);
}

extern "C" void kernel_launch(void* const* d_in, const int* in_sizes, int n_in,
                              void* d_out, int out_size, void* d_ws, size_t ws_size,
                              hipStream_t stream) {
    const float* x    = (const float*)d_in[0];
    const int*   ei   = (const int*)  d_in[1];
    const float* Wl   = (const float*)d_in[2];
    const float* bl   = (const float*)d_in[3];
    const float* Wr   = (const float*)d_in[4];
    const float* br   = (const float*)d_in[5];
    const float* att  = (const float*)d_in[6];
    const float* bias = (const float*)d_in[7];
    const float* Wp   = (const float*)d_in[8];
    const float* bp   = (const float*)d_in[9];
    const float* gam  = (const float*)d_in[10];
    const float* bet  = (const float*)d_in[11];
    const int* src = ei;            // edge_index[0]
    const int* dst = ei + E_;       // edge_index[1]

    float* ws = (float*)d_ws;
    float*    xl    = ws;                                   // T*N*HC = 5.12M f
    float*    xr    = xl    + (size_t)T_ * N_ * HC_;        // 5.12M f
    float*    alpha = xr    + (size_t)T_ * N_ * HC_;        // E*T*H = 1.28M f
    unsigned* amax  = (unsigned*)(alpha + (size_t)E_ * T_ * H_);  // T*N*H
    float*    denom = (float*)(amax + (size_t)T_ * N_ * H_);      // T*N*H
    float*    agg   = denom + (size_t)T_ * N_ * H_;         // T*N*HC = 5.12M f

    // zero amax(enc sentinel) + denom + agg in one contiguous memset
    const size_t zero_bytes =
        ((size_t)T_ * N_ * H_ * 2 + (size_t)T_ * N_ * HC_) * sizeof(float);
    hipMemsetAsync(amax, 0, zero_bytes, stream);

    gemm_lr   <<<T_ * N_,        256, 0, stream>>>(x, Wl, bl, Wr, br, xl, xr);
    edge_alpha<<<(E_ * T_) / 4,  256, 0, stream>>>(xl, xr, src, dst, att, alpha, amax);
    edge_exp  <<<(E_ * T_ * H_) / 256, 256, 0, stream>>>(dst, amax, alpha, denom);
    edge_agg  <<<(E_ * T_) / 4,  256, 0, stream>>>(xl, src, dst, alpha, denom, agg);
    epilogue  <<<T_ * N_,         64, 0, stream>>>(agg, bias, Wp, bp, x, gam, bet,
                                                   (float*)d_out);
}

// Round 2
// 389.491 us; speedup vs baseline: 3.5615x; 3.5615x over previous
//
#include <hip/hip_runtime.h>

#define T_  2
#define N_  10000
#define C_  64
#define H_  4
#define Co_ 64
#define E_  160000
#define HC_ 256          // H*Co
#define NEG_SLOPE 0.2f
#define LN_EPS 1e-5f

__device__ __forceinline__ float lrelu(float v) {
    return v >= 0.f ? v : NEG_SLOPE * v;
}

// ---- Pass A: x_l = x@W_l + b_l, x_r = x@W_r + b_r  (one block per (t,n) row)
__global__ __launch_bounds__(256) void gemm_lr(
        const float* __restrict__ x, const float* __restrict__ Wl,
        const float* __restrict__ bl, const float* __restrict__ Wr,
        const float* __restrict__ br, float* __restrict__ xl,
        float* __restrict__ xr) {
    __shared__ float xs[C_];
    const int row = blockIdx.x;        // t*N + n
    const int j   = threadIdx.x;       // 0..255 output column
    if (j < C_) xs[j] = x[(size_t)row * C_ + j];
    __syncthreads();
    float accl = bl[j], accr = br[j];
    #pragma unroll 8
    for (int c = 0; c < C_; ++c) {
        const float xv = xs[c];
        accl = fmaf(xv, Wl[c * HC_ + j], accl);
        accr = fmaf(xv, Wr[c * HC_ + j], accr);
    }
    xl[(size_t)row * HC_ + j] = accl;
    xr[(size_t)row * HC_ + j] = accr;
}

// ---- Pass B: alpha[e,t,h] (one 64-lane wave per (e,t)); no atomics
__global__ __launch_bounds__(256) void edge_alpha(
        const float* __restrict__ xl, const float* __restrict__ xr,
        const int* __restrict__ src, const int* __restrict__ dst,
        const float* __restrict__ att, float* __restrict__ alpha) {
    const int wid  = blockIdx.x * 4 + (threadIdx.x >> 6);  // p = e*T + t
    const int lane = threadIdx.x & 63;
    const int e = wid / T_, t = wid % T_;
    const int s = src[e], d = dst[e];
    const float4 xj = *(const float4*)&xl[((size_t)t * N_ + s) * HC_ + lane * 4];
    const float4 xi = *(const float4*)&xr[((size_t)t * N_ + d) * HC_ + lane * 4];
    const float4 av = *(const float4*)&att[lane * 4];
    float part = lrelu(xi.x + xj.x) * av.x + lrelu(xi.y + xj.y) * av.y +
                 lrelu(xi.z + xj.z) * av.z + lrelu(xi.w + xj.w) * av.w;
    part += __shfl_xor(part, 1, 64);
    part += __shfl_xor(part, 2, 64);
    part += __shfl_xor(part, 4, 64);
    part += __shfl_xor(part, 8, 64);
    if ((lane & 15) == 0)
        alpha[(size_t)wid * H_ + (lane >> 4)] = part;
}

// ---- CSR build: histogram of dst
__global__ __launch_bounds__(256) void hist_kernel(
        const int* __restrict__ dst, int* __restrict__ count) {
    const int e = blockIdx.x * 256 + threadIdx.x;
    if (e < E_) atomicAdd(&count[dst[e]], 1);
}

// ---- CSR build: exclusive scan over N_ counts (single block)
__global__ __launch_bounds__(1024) void scan_kernel(
        const int* __restrict__ count, int* __restrict__ row_start) {
    __shared__ int part[1024];
    const int tid = threadIdx.x;
    const int base = tid * 10;             // 1024*10 >= N_
    int local[10];
    int s = 0;
    #pragma unroll
    for (int i = 0; i < 10; ++i) {
        const int idx = base + i;
        const int v = (idx < N_) ? count[idx] : 0;
        local[i] = s;
        s += v;
    }
    part[tid] = s;
    __syncthreads();
    for (int off = 1; off < 1024; off <<= 1) {
        const int v = (tid >= off) ? part[tid - off] : 0;
        __syncthreads();
        part[tid] += v;
        __syncthreads();
    }
    const int prefix = (tid > 0) ? part[tid - 1] : 0;
    #pragma unroll
    for (int i = 0; i < 10; ++i) {
        const int idx = base + i;
        if (idx < N_) row_start[idx] = prefix + local[i];
    }
    if (tid == 1023) row_start[N_] = part[1023];
}

// ---- CSR build: scatter edge ids into dst-sorted order
__global__ __launch_bounds__(256) void scatter_kernel(
        const int* __restrict__ dst, const int* __restrict__ row_start,
        int* __restrict__ cursor, int* __restrict__ perm) {
    const int e = blockIdx.x * 256 + threadIdx.x;
    if (e >= E_) return;
    const int d = dst[e];
    const int pos = row_start[d] + atomicAdd(&cursor[d], 1);
    perm[pos] = e;
}

// ---- Pass D: per-(t,n) softmax + aggregation, no atomics
#define CHUNK 64
__global__ __launch_bounds__(256) void node_agg(
        const float* __restrict__ xl, const float* __restrict__ alpha,
        const int* __restrict__ src, const int* __restrict__ perm,
        const int* __restrict__ row_start, float* __restrict__ agg) {
    __shared__ float mx[H_], inv_dn[H_];
    __shared__ float w_lds[CHUNK * H_];
    __shared__ int   src_lds[CHUNK];
    const int row = blockIdx.x;          // t*N + n
    const int t = row / N_, n = row % N_;
    const int beg = row_start[n], end = row_start[n + 1];
    const int tid  = threadIdx.x;
    const int h    = tid >> 6;           // head for phase 1
    const int lane = tid & 63;

    // phase 1a: per-head max over segment
    float m = -INFINITY;
    for (int k = beg + lane; k < end; k += 64)
        m = fmaxf(m, alpha[((size_t)perm[k] * T_ + t) * H_ + h]);
    #pragma unroll
    for (int off = 1; off < 64; off <<= 1)
        m = fmaxf(m, __shfl_xor(m, off, 64));
    if (lane == 0) mx[h] = m;
    __syncthreads();
    // phase 1b: per-head sum of exp
    const float mh = mx[h];
    float sum = 0.f;
    for (int k = beg + lane; k < end; k += 64)
        sum += __expf(alpha[((size_t)perm[k] * T_ + t) * H_ + h] - mh);
    #pragma unroll
    for (int off = 1; off < 64; off <<= 1)
        sum += __shfl_xor(sum, off, 64);
    if (lane == 0) inv_dn[h] = 1.f / sum;
    __syncthreads();

    // phase 2: chunked weighted aggregation; thread j owns channel j
    const int jh = tid >> 6;             // head of this channel
    float acc = 0.f;
    for (int cs = beg; cs < end; cs += CHUNK) {
        const int cnt = min(CHUNK, end - cs);
        {   // tid = c*4 + hh covers CHUNK edges x 4 heads
            const int c = tid >> 2, hh = tid & 3;
            if (c < cnt) {
                const int e = perm[cs + c];
                w_lds[c * H_ + hh] =
                    __expf(alpha[((size_t)e * T_ + t) * H_ + hh] - mx[hh]) *
                    inv_dn[hh];
                if (hh == 0) src_lds[c] = src[e];
            }
        }
        __syncthreads();
        for (int c = 0; c < cnt; ++c)
            acc = fmaf(w_lds[c * H_ + jh],
                       xl[((size_t)t * N_ + src_lds[c]) * HC_ + tid], acc);
        __syncthreads();
    }
    agg[(size_t)row * HC_ + tid] = acc;
}

// ---- Pass E: relu(agg+bias) @ W_proj + b_proj + x -> LN -> relu
__global__ __launch_bounds__(64) void epilogue(
        const float* __restrict__ agg, const float* __restrict__ bias,
        const float* __restrict__ Wp, const float* __restrict__ bp,
        const float* __restrict__ x, const float* __restrict__ gamma,
        const float* __restrict__ beta, float* __restrict__ out) {
    __shared__ float sh[HC_];
    const int row = blockIdx.x;      // t*N + n
    const int o   = threadIdx.x;     // 0..63
    #pragma unroll
    for (int k = o; k < HC_; k += 64)
        sh[k] = fmaxf(agg[(size_t)row * HC_ + k] + bias[k], 0.f);
    __syncthreads();
    float acc = bp[o] + x[(size_t)row * C_ + o];
    #pragma unroll 8
    for (int k = 0; k < HC_; ++k)
        acc = fmaf(sh[k], Wp[k * Co_ + o], acc);
    float s1 = acc;
    #pragma unroll
    for (int off = 1; off < 64; off <<= 1) s1 += __shfl_xor(s1, off, 64);
    const float mu = s1 * (1.f / 64.f);
    const float dv = acc - mu;
    float s2 = dv * dv;
    #pragma unroll
    for (int off = 1; off < 64; off <<= 1) s2 += __shfl_xor(s2, off, 64);
    const float var = s2 * (1.f / 64.f);
    const float y = dv * rsqrtf(var + LN_EPS) * gamma[o] + beta[o];
    out[(size_t)row * C_ + o] = fmaxf(y, 0.f);
}

extern "C" void kernel_launch(void* const* d_in, const int* in_sizes, int n_in,
                              void* d_out, int out_size, void* d_ws, size_t ws_size,
                              hipStream_t stream) {
    const float* x    = (const float*)d_in[0];
    const int*   ei   = (const int*)  d_in[1];
    const float* Wl   = (const float*)d_in[2];
    const float* bl   = (const float*)d_in[3];
    const float* Wr   = (const float*)d_in[4];
    const float* br   = (const float*)d_in[5];
    const float* att  = (const float*)d_in[6];
    const float* bias = (const float*)d_in[7];
    const float* Wp   = (const float*)d_in[8];
    const float* bp   = (const float*)d_in[9];
    const float* gam  = (const float*)d_in[10];
    const float* bet  = (const float*)d_in[11];
    const int* src = ei;            // edge_index[0]
    const int* dst = ei + E_;       // edge_index[1]

    float* ws = (float*)d_ws;
    float* xl    = ws;                                   // T*N*HC
    float* xr    = xl    + (size_t)T_ * N_ * HC_;
    float* alpha = xr    + (size_t)T_ * N_ * HC_;        // E*T*H
    float* agg   = alpha + (size_t)E_ * T_ * H_;         // T*N*HC
    int* row_start = (int*)(agg + (size_t)T_ * N_ * HC_);  // N+1
    int* count     = row_start + (N_ + 1);                 // N
    int* cursor    = count + N_;                           // N
    int* perm      = cursor + N_;                          // E

    // zero count + cursor (contiguous)
    hipMemsetAsync(count, 0, 2 * N_ * sizeof(int), stream);

    hist_kernel   <<<(E_ + 255) / 256, 256, 0, stream>>>(dst, count);
    scan_kernel   <<<1, 1024, 0, stream>>>(count, row_start);
    scatter_kernel<<<(E_ + 255) / 256, 256, 0, stream>>>(dst, row_start, cursor, perm);

    gemm_lr   <<<T_ * N_,       256, 0, stream>>>(x, Wl, bl, Wr, br, xl, xr);
    edge_alpha<<<(E_ * T_) / 4, 256, 0, stream>>>(xl, xr, src, dst, att, alpha);
    node_agg  <<<T_ * N_,       256, 0, stream>>>(xl, alpha, src, perm, row_start, agg);
    epilogue  <<<T_ * N_,        64, 0, stream>>>(agg, bias, Wp, bp, x, gam, bet,
                                                  (float*)d_out);
}

// Round 3
// 348.705 us; speedup vs baseline: 3.9781x; 1.1170x over previous
//
#include <hip/hip_runtime.h>

#define T_  2
#define N_  10000
#define C_  64
#define H_  4
#define Co_ 64
#define E_  160000
#define HC_ 256          // H*Co
#define NEG_SLOPE 0.2f
#define LN_EPS 1e-5f
#define XLPAD 260        // LDS row stride for staged xl rows (see bank math)

__device__ __forceinline__ float lrelu(float v) {
    return v >= 0.f ? v : NEG_SLOPE * v;
}

// ---- Pass A: x_l/x_r = x@W + b, 8 rows per block (W read amortized 8x)
__global__ __launch_bounds__(256) void gemm_lr(
        const float* __restrict__ x, const float* __restrict__ Wl,
        const float* __restrict__ bl, const float* __restrict__ Wr,
        const float* __restrict__ br, float* __restrict__ xl,
        float* __restrict__ xr) {
    __shared__ float xs[8 * C_];          // 2 KB
    const int r0 = blockIdx.x * 8;
    const int j  = threadIdx.x;           // output column 0..255
    ((float2*)xs)[j] = ((const float2*)(x + (size_t)r0 * C_))[j];
    __syncthreads();
    const float blj = bl[j], brj = br[j];
    float accl[8], accr[8];
    #pragma unroll
    for (int r = 0; r < 8; ++r) { accl[r] = blj; accr[r] = brj; }
    #pragma unroll 4
    for (int c = 0; c < C_; ++c) {
        const float wl = Wl[c * HC_ + j];
        const float wr = Wr[c * HC_ + j];
        #pragma unroll
        for (int r = 0; r < 8; ++r) {
            const float xv = xs[r * C_ + c];
            accl[r] = fmaf(xv, wl, accl[r]);
            accr[r] = fmaf(xv, wr, accr[r]);
        }
    }
    #pragma unroll
    for (int r = 0; r < 8; ++r) {
        xl[(size_t)(r0 + r) * HC_ + j] = accl[r];
        xr[(size_t)(r0 + r) * HC_ + j] = accr[r];
    }
}

// ---- CSR build
__global__ __launch_bounds__(256) void hist_kernel(
        const int* __restrict__ dst, int* __restrict__ count) {
    const int e = blockIdx.x * 256 + threadIdx.x;
    if (e < E_) atomicAdd(&count[dst[e]], 1);
}

__global__ __launch_bounds__(1024) void scan_kernel(
        const int* __restrict__ count, int* __restrict__ row_start) {
    __shared__ int part[1024];
    const int tid = threadIdx.x;
    const int base = tid * 10;
    int local[10];
    int s = 0;
    #pragma unroll
    for (int i = 0; i < 10; ++i) {
        const int idx = base + i;
        const int v = (idx < N_) ? count[idx] : 0;
        local[i] = s;
        s += v;
    }
    part[tid] = s;
    __syncthreads();
    for (int off = 1; off < 1024; off <<= 1) {
        const int v = (tid >= off) ? part[tid - off] : 0;
        __syncthreads();
        part[tid] += v;
        __syncthreads();
    }
    const int prefix = (tid > 0) ? part[tid - 1] : 0;
    #pragma unroll
    for (int i = 0; i < 10; ++i) {
        const int idx = base + i;
        if (idx < N_) row_start[idx] = prefix + local[i];
    }
    if (tid == 1023) row_start[N_] = part[1023];
}

__global__ __launch_bounds__(256) void scatter_kernel(
        const int* __restrict__ src, const int* __restrict__ dst,
        const int* __restrict__ row_start, int* __restrict__ cursor,
        int* __restrict__ perm_src) {
    const int e = blockIdx.x * 256 + threadIdx.x;
    if (e >= E_) return;
    const int d = dst[e];
    const int pos = row_start[d] + atomicAdd(&cursor[d], 1);
    perm_src[pos] = src[e];
}

// ---- Fused per-node attention: alpha + online softmax + aggregation
__global__ __launch_bounds__(256) void node_agg(
        const float* __restrict__ xl, const float* __restrict__ xr,
        const float* __restrict__ att, const int* __restrict__ perm_src,
        const int* __restrict__ row_start, float* __restrict__ agg) {
    __shared__ float xl_lds[32 * XLPAD];     // 32 staged src rows, padded
    __shared__ float xr_lds[HC_], att_lds[HC_];
    __shared__ float alpha_lds[32 * H_], w_lds[32 * H_];
    __shared__ float m_sh[H_], s_sh[H_], scale_sh[H_];
    const int row = blockIdx.x;              // t*N + n
    const int t = row / N_, n = row % N_;
    const int beg = row_start[n], end = row_start[n + 1];
    const int tid = threadIdx.x;
    const int jh  = tid >> 6;                // head of channel tid

    xr_lds[tid]  = xr[(size_t)row * HC_ + tid];
    att_lds[tid] = att[tid];
    if (tid < H_) { m_sh[tid] = -INFINITY; s_sh[tid] = 0.f; }
    __syncthreads();

    float acc = 0.f;
    for (int base = beg; base < end; base += 32) {
        const int cnt = min(32, end - base);
        // stage chunk's src rows into LDS (coalesced 1 KB segments)
        #pragma unroll
        for (int i = 0; i < 8; ++i) {
            const int slot = i * 256 + tid;
            const int e = slot >> 6, f4 = slot & 63;
            if (e < cnt) {
                const int s = perm_src[base + e];
                const float4 v = ((const float4*)
                    &xl[((size_t)t * N_ + s) * HC_])[f4];
                ((float4*)&xl_lds[e * XLPAD])[f4] = v;
            }
        }
        __syncthreads();
        // dot: 8 threads per edge, thread sub owns channels sub+8j
        {
            const int e = tid >> 3, sub = tid & 7;
            float p0 = 0.f, p1 = 0.f, p2 = 0.f, p3 = 0.f;
            if (e < cnt) {
                const float* xle = &xl_lds[e * XLPAD];
                #pragma unroll
                for (int j = 0; j < 8; ++j) {
                    const int c0 = sub + 8 * j;
                    const int c1 = c0 + 64, c2 = c0 + 128, c3 = c0 + 192;
                    p0 = fmaf(lrelu(xr_lds[c0] + xle[c0]), att_lds[c0], p0);
                    p1 = fmaf(lrelu(xr_lds[c1] + xle[c1]), att_lds[c1], p1);
                    p2 = fmaf(lrelu(xr_lds[c2] + xle[c2]), att_lds[c2], p2);
                    p3 = fmaf(lrelu(xr_lds[c3] + xle[c3]), att_lds[c3], p3);
                }
            }
            #pragma unroll
            for (int m = 1; m < 8; m <<= 1) {
                p0 += __shfl_xor(p0, m, 64);
                p1 += __shfl_xor(p1, m, 64);
                p2 += __shfl_xor(p2, m, 64);
                p3 += __shfl_xor(p3, m, 64);
            }
            if (e < cnt && sub < 4) {
                const float v = (sub == 0) ? p0 : (sub == 1) ? p1
                              : (sub == 2) ? p2 : p3;
                alpha_lds[e * H_ + sub] = v;
            }
        }
        __syncthreads();
        // online-softmax state update (one thread per head)
        if (tid < H_) {
            const int h = tid;
            const float m_old = m_sh[h];
            float cm = -INFINITY;
            for (int c = 0; c < cnt; ++c)
                cm = fmaxf(cm, alpha_lds[c * H_ + h]);
            const float m_new = fmaxf(m_old, cm);
            const float sc = __expf(m_old - m_new);
            float ssum = 0.f;
            for (int c = 0; c < cnt; ++c) {
                const float w = __expf(alpha_lds[c * H_ + h] - m_new);
                w_lds[c * H_ + h] = w;
                ssum += w;
            }
            m_sh[h] = m_new;
            s_sh[h] = s_sh[h] * sc + ssum;
            scale_sh[h] = sc;
        }
        __syncthreads();
        // accumulate: thread tid owns channel tid
        acc *= scale_sh[jh];
        for (int c = 0; c < cnt; ++c)
            acc = fmaf(w_lds[c * H_ + jh], xl_lds[c * XLPAD + tid], acc);
        __syncthreads();
    }
    const float val = (end > beg) ? acc / s_sh[jh] : 0.f;
    agg[(size_t)row * HC_ + tid] = val;
}

// ---- Pass E: relu(agg+bias) @ W_proj + b_proj + x -> LN -> relu
// 32 rows per block (4 waves x 8 rows); Wp read amortized
__global__ __launch_bounds__(256) void epilogue(
        const float* __restrict__ agg, const float* __restrict__ bias,
        const float* __restrict__ Wp, const float* __restrict__ bp,
        const float* __restrict__ x, const float* __restrict__ gamma,
        const float* __restrict__ beta, float* __restrict__ out) {
    __shared__ float sh[32 * HC_];       // 32 KB
    const int r0  = blockIdx.x * 32;
    const int tid = threadIdx.x;
    #pragma unroll
    for (int i = 0; i < 8; ++i) {
        const int slot = i * 256 + tid;          // float4 index
        const int r = slot >> 6, f4 = slot & 63;
        float4 v = ((const float4*)&agg[(size_t)(r0 + r) * HC_])[f4];
        const float4 b = ((const float4*)bias)[f4];
        v.x = fmaxf(v.x + b.x, 0.f); v.y = fmaxf(v.y + b.y, 0.f);
        v.z = fmaxf(v.z + b.z, 0.f); v.w = fmaxf(v.w + b.w, 0.f);
        ((float4*)sh)[slot] = v;
    }
    __syncthreads();
    const int wave = tid >> 6, o = tid & 63;
    const int rbase = wave * 8;                  // local row base
    const float bpo = bp[o];
    float acc[8];
    #pragma unroll
    for (int r = 0; r < 8; ++r)
        acc[r] = bpo + x[(size_t)(r0 + rbase + r) * C_ + o];
    for (int k = 0; k < HC_; k += 4) {
        const float w0 = Wp[(k + 0) * Co_ + o];
        const float w1 = Wp[(k + 1) * Co_ + o];
        const float w2 = Wp[(k + 2) * Co_ + o];
        const float w3 = Wp[(k + 3) * Co_ + o];
        #pragma unroll
        for (int r = 0; r < 8; ++r) {
            const float4 s4 = ((const float4*)&sh[(rbase + r) * HC_])[k >> 2];
            acc[r] = fmaf(s4.x, w0, acc[r]);
            acc[r] = fmaf(s4.y, w1, acc[r]);
            acc[r] = fmaf(s4.z, w2, acc[r]);
            acc[r] = fmaf(s4.w, w3, acc[r]);
        }
    }
    const float go = gamma[o], bo = beta[o];
    #pragma unroll
    for (int r = 0; r < 8; ++r) {
        float s1 = acc[r];
        #pragma unroll
        for (int off = 1; off < 64; off <<= 1) s1 += __shfl_xor(s1, off, 64);
        const float mu = s1 * (1.f / 64.f);
        const float dv = acc[r] - mu;
        float s2 = dv * dv;
        #pragma unroll
        for (int off = 1; off < 64; off <<= 1) s2 += __shfl_xor(s2, off, 64);
        const float var = s2 * (1.f / 64.f);
        const float y = dv * rsqrtf(var + LN_EPS) * go + bo;
        out[(size_t)(r0 + rbase + r) * C_ + o] = fmaxf(y, 0.f);
    }
}

extern "C" void kernel_launch(void* const* d_in, const int* in_sizes, int n_in,
                              void* d_out, int out_size, void* d_ws, size_t ws_size,
                              hipStream_t stream) {
    const float* x    = (const float*)d_in[0];
    const int*   ei   = (const int*)  d_in[1];
    const float* Wl   = (const float*)d_in[2];
    const float* bl   = (const float*)d_in[3];
    const float* Wr   = (const float*)d_in[4];
    const float* br   = (const float*)d_in[5];
    const float* att  = (const float*)d_in[6];
    const float* bias = (const float*)d_in[7];
    const float* Wp   = (const float*)d_in[8];
    const float* bp   = (const float*)d_in[9];
    const float* gam  = (const float*)d_in[10];
    const float* bet  = (const float*)d_in[11];
    const int* src = ei;            // edge_index[0]
    const int* dst = ei + E_;       // edge_index[1]

    float* ws = (float*)d_ws;
    float* xl  = ws;                                   // T*N*HC
    float* xr  = xl + (size_t)T_ * N_ * HC_;
    float* agg = xr + (size_t)T_ * N_ * HC_;           // T*N*HC
    int* row_start = (int*)(agg + (size_t)T_ * N_ * HC_);  // N+1
    int* count     = row_start + (N_ + 1);                 // N
    int* cursor    = count + N_;                           // N
    int* perm_src  = cursor + N_;                          // E

    hipMemsetAsync(count, 0, 2 * N_ * sizeof(int), stream);

    hist_kernel   <<<(E_ + 255) / 256, 256, 0, stream>>>(dst, count);
    scan_kernel   <<<1, 1024, 0, stream>>>(count, row_start);
    scatter_kernel<<<(E_ + 255) / 256, 256, 0, stream>>>(src, dst, row_start,
                                                         cursor, perm_src);
    gemm_lr <<<T_ * N_ / 8,  256, 0, stream>>>(x, Wl, bl, Wr, br, xl, xr);
    node_agg<<<T_ * N_,      256, 0, stream>>>(xl, xr, att, perm_src,
                                               row_start, agg);
    epilogue<<<T_ * N_ / 32, 256, 0, stream>>>(agg, bias, Wp, bp, x, gam, bet,
                                               (float*)d_out);
}

// Round 4
// 223.704 us; speedup vs baseline: 6.2010x; 1.5588x over previous
//
#include <hip/hip_runtime.h>

#define T_  2
#define N_  10000
#define C_  64
#define H_  4
#define Co_ 64
#define E_  160000
#define HC_ 256          // H*Co
#define NEG_SLOPE 0.2f
#define LN_EPS 1e-5f

__device__ __forceinline__ float lrelu(float v) {
    return fmaxf(v, NEG_SLOPE * v);      // valid since NEG_SLOPE < 1
}

// ---- Pass A: x_l/x_r = x@W + b, 8 rows per block (W read amortized 8x)
__global__ __launch_bounds__(256) void gemm_lr(
        const float* __restrict__ x, const float* __restrict__ Wl,
        const float* __restrict__ bl, const float* __restrict__ Wr,
        const float* __restrict__ br, float* __restrict__ xl,
        float* __restrict__ xr) {
    __shared__ float xs[8 * C_];          // 2 KB
    const int r0 = blockIdx.x * 8;
    const int j  = threadIdx.x;           // output column 0..255
    ((float2*)xs)[j] = ((const float2*)(x + (size_t)r0 * C_))[j];
    __syncthreads();
    const float blj = bl[j], brj = br[j];
    float accl[8], accr[8];
    #pragma unroll
    for (int r = 0; r < 8; ++r) { accl[r] = blj; accr[r] = brj; }
    #pragma unroll 4
    for (int c = 0; c < C_; ++c) {
        const float wl = Wl[c * HC_ + j];
        const float wr = Wr[c * HC_ + j];
        #pragma unroll
        for (int r = 0; r < 8; ++r) {
            const float xv = xs[r * C_ + c];
            accl[r] = fmaf(xv, wl, accl[r]);
            accr[r] = fmaf(xv, wr, accr[r]);
        }
    }
    #pragma unroll
    for (int r = 0; r < 8; ++r) {
        xl[(size_t)(r0 + r) * HC_ + j] = accl[r];
        xr[(size_t)(r0 + r) * HC_ + j] = accr[r];
    }
}

// ---- CSR build
__global__ __launch_bounds__(256) void hist_kernel(
        const int* __restrict__ dst, int* __restrict__ count) {
    const int e = blockIdx.x * 256 + threadIdx.x;
    if (e < E_) atomicAdd(&count[dst[e]], 1);
}

__global__ __launch_bounds__(1024) void scan_kernel(
        const int* __restrict__ count, int* __restrict__ row_start) {
    __shared__ int part[1024];
    const int tid = threadIdx.x;
    const int base = tid * 10;
    int local[10];
    int s = 0;
    #pragma unroll
    for (int i = 0; i < 10; ++i) {
        const int idx = base + i;
        const int v = (idx < N_) ? count[idx] : 0;
        local[i] = s;
        s += v;
    }
    part[tid] = s;
    __syncthreads();
    for (int off = 1; off < 1024; off <<= 1) {
        const int v = (tid >= off) ? part[tid - off] : 0;
        __syncthreads();
        part[tid] += v;
        __syncthreads();
    }
    const int prefix = (tid > 0) ? part[tid - 1] : 0;
    #pragma unroll
    for (int i = 0; i < 10; ++i) {
        const int idx = base + i;
        if (idx < N_) row_start[idx] = prefix + local[i];
    }
    if (tid == 1023) row_start[N_] = part[1023];
}

__global__ __launch_bounds__(256) void scatter_kernel(
        const int* __restrict__ src, const int* __restrict__ dst,
        const int* __restrict__ row_start, int* __restrict__ cursor,
        int* __restrict__ perm_src) {
    const int e = blockIdx.x * 256 + threadIdx.x;
    if (e >= E_) return;
    const int d = dst[e];
    const int pos = row_start[d] + atomicAdd(&cursor[d], 1);
    perm_src[pos] = src[e];
}

// ---- Fused per-node attention: one 64-lane wave per (t,n), no LDS/barriers
__global__ __launch_bounds__(256) void node_agg(
        const float* __restrict__ xl, const float* __restrict__ xr,
        const float* __restrict__ att, const int* __restrict__ perm_src,
        const int* __restrict__ row_start, float* __restrict__ agg) {
    const int wid  = blockIdx.x * 4 + (threadIdx.x >> 6);   // t*N + n
    const int lane = threadIdx.x & 63;
    const int t = wid / N_, n = wid % N_;
    const int beg = row_start[n], end = row_start[n + 1];
    const float4 xi = ((const float4*)&xr[(size_t)wid * HC_])[lane];
    const float4 av = ((const float4*)att)[lane];
    const float* xlt = xl + (size_t)t * N_ * HC_;

    float m = -INFINITY, s = 0.f;
    float4 acc = make_float4(0.f, 0.f, 0.f, 0.f);

    for (int base = beg; base < end; base += 64) {
        const int cnt = min(64, end - base);
        const int myidx = (lane < cnt) ? perm_src[base + lane] : 0;
        // prefetch first row of chunk
        float4 xj = ((const float4*)&xlt[(size_t)__shfl(myidx, 0, 64) * HC_])[lane];
        for (int k = 0; k < cnt; ++k) {
            const float4 cur = xj;
            if (k + 1 < cnt) {
                const int sn = __shfl(myidx, k + 1, 64);
                xj = ((const float4*)&xlt[(size_t)sn * HC_])[lane];
            }
            // alpha: dot over this lane's 4 channels, reduce over 16-lane head
            float p =      lrelu(xi.x + cur.x) * av.x;
            p = fmaf(lrelu(xi.y + cur.y), av.y, p);
            p = fmaf(lrelu(xi.z + cur.z), av.z, p);
            p = fmaf(lrelu(xi.w + cur.w), av.w, p);
            p += __shfl_xor(p, 1, 64);
            p += __shfl_xor(p, 2, 64);
            p += __shfl_xor(p, 4, 64);
            p += __shfl_xor(p, 8, 64);
            // online softmax (uniform within each 16-lane head group)
            const float m_new = fmaxf(m, p);
            const float sc = __expf(m - m_new);
            const float w  = __expf(p - m_new);
            s = fmaf(s, sc, w);
            acc.x = fmaf(w, cur.x, acc.x * sc);
            acc.y = fmaf(w, cur.y, acc.y * sc);
            acc.z = fmaf(w, cur.z, acc.z * sc);
            acc.w = fmaf(w, cur.w, acc.w * sc);
            m = m_new;
        }
    }
    if (end > beg) {
        const float inv = 1.f / s;
        acc.x *= inv; acc.y *= inv; acc.z *= inv; acc.w *= inv;
    }
    ((float4*)&agg[(size_t)wid * HC_])[lane] = acc;
}

// ---- Pass E: relu(agg+bias) @ W_proj + b_proj + x -> LN -> relu
// 32 rows per block (4 waves x 8 rows); Wp read amortized
__global__ __launch_bounds__(256) void epilogue(
        const float* __restrict__ agg, const float* __restrict__ bias,
        const float* __restrict__ Wp, const float* __restrict__ bp,
        const float* __restrict__ x, const float* __restrict__ gamma,
        const float* __restrict__ beta, float* __restrict__ out) {
    __shared__ float sh[32 * HC_];       // 32 KB
    const int r0  = blockIdx.x * 32;
    const int tid = threadIdx.x;
    #pragma unroll
    for (int i = 0; i < 8; ++i) {
        const int slot = i * 256 + tid;          // float4 index
        const int r = slot >> 6, f4 = slot & 63;
        float4 v = ((const float4*)&agg[(size_t)(r0 + r) * HC_])[f4];
        const float4 b = ((const float4*)bias)[f4];
        v.x = fmaxf(v.x + b.x, 0.f); v.y = fmaxf(v.y + b.y, 0.f);
        v.z = fmaxf(v.z + b.z, 0.f); v.w = fmaxf(v.w + b.w, 0.f);
        ((float4*)sh)[slot] = v;
    }
    __syncthreads();
    const int wave = tid >> 6, o = tid & 63;
    const int rbase = wave * 8;                  // local row base
    const float bpo = bp[o];
    float acc[8];
    #pragma unroll
    for (int r = 0; r < 8; ++r)
        acc[r] = bpo + x[(size_t)(r0 + rbase + r) * C_ + o];
    for (int k = 0; k < HC_; k += 4) {
        const float w0 = Wp[(k + 0) * Co_ + o];
        const float w1 = Wp[(k + 1) * Co_ + o];
        const float w2 = Wp[(k + 2) * Co_ + o];
        const float w3 = Wp[(k + 3) * Co_ + o];
        #pragma unroll
        for (int r = 0; r < 8; ++r) {
            const float4 s4 = ((const float4*)&sh[(rbase + r) * HC_])[k >> 2];
            acc[r] = fmaf(s4.x, w0, acc[r]);
            acc[r] = fmaf(s4.y, w1, acc[r]);
            acc[r] = fmaf(s4.z, w2, acc[r]);
            acc[r] = fmaf(s4.w, w3, acc[r]);
        }
    }
    const float go = gamma[o], bo = beta[o];
    #pragma unroll
    for (int r = 0; r < 8; ++r) {
        float s1 = acc[r];
        #pragma unroll
        for (int off = 1; off < 64; off <<= 1) s1 += __shfl_xor(s1, off, 64);
        const float mu = s1 * (1.f / 64.f);
        const float dv = acc[r] - mu;
        float s2 = dv * dv;
        #pragma unroll
        for (int off = 1; off < 64; off <<= 1) s2 += __shfl_xor(s2, off, 64);
        const float var = s2 * (1.f / 64.f);
        const float y = dv * rsqrtf(var + LN_EPS) * go + bo;
        out[(size_t)(r0 + rbase + r) * C_ + o] = fmaxf(y, 0.f);
    }
}

extern "C" void kernel_launch(void* const* d_in, const int* in_sizes, int n_in,
                              void* d_out, int out_size, void* d_ws, size_t ws_size,
                              hipStream_t stream) {
    const float* x    = (const float*)d_in[0];
    const int*   ei   = (const int*)  d_in[1];
    const float* Wl   = (const float*)d_in[2];
    const float* bl   = (const float*)d_in[3];
    const float* Wr   = (const float*)d_in[4];
    const float* br   = (const float*)d_in[5];
    const float* att  = (const float*)d_in[6];
    const float* bias = (const float*)d_in[7];
    const float* Wp   = (const float*)d_in[8];
    const float* bp   = (const float*)d_in[9];
    const float* gam  = (const float*)d_in[10];
    const float* bet  = (const float*)d_in[11];
    const int* src = ei;            // edge_index[0]
    const int* dst = ei + E_;       // edge_index[1]

    float* ws = (float*)d_ws;
    float* xl  = ws;                                   // T*N*HC
    float* xr  = xl + (size_t)T_ * N_ * HC_;
    float* agg = xr + (size_t)T_ * N_ * HC_;           // T*N*HC
    int* row_start = (int*)(agg + (size_t)T_ * N_ * HC_);  // N+1
    int* count     = row_start + (N_ + 1);                 // N
    int* cursor    = count + N_;                           // N
    int* perm_src  = cursor + N_;                          // E

    hipMemsetAsync(count, 0, 2 * N_ * sizeof(int), stream);

    hist_kernel   <<<(E_ + 255) / 256, 256, 0, stream>>>(dst, count);
    scan_kernel   <<<1, 1024, 0, stream>>>(count, row_start);
    scatter_kernel<<<(E_ + 255) / 256, 256, 0, stream>>>(src, dst, row_start,
                                                         cursor, perm_src);
    gemm_lr <<<T_ * N_ / 8,  256, 0, stream>>>(x, Wl, bl, Wr, br, xl, xr);
    node_agg<<<T_ * N_ / 4,  256, 0, stream>>>(xl, xr, att, perm_src,
                                               row_start, agg);
    epilogue<<<T_ * N_ / 32, 256, 0, stream>>>(agg, bias, Wp, bp, x, gam, bet,
                                               (float*)d_out);
}

// Round 5
// 209.400 us; speedup vs baseline: 6.6246x; 1.0683x over previous
//
#include <hip/hip_runtime.h>

#define T_  2
#define N_  10000
#define C_  64
#define H_  4
#define Co_ 64
#define E_  160000
#define HC_ 256          // H*Co
#define NEG_SLOPE 0.2f
#define LN_EPS 1e-5f

__device__ __forceinline__ float lrelu(float v) {
    return fmaxf(v, NEG_SLOPE * v);      // valid since NEG_SLOPE < 1
}

// ---- Pass A: x_l/x_r = x@W + b, 16 rows per block.
// Thread -> (row-half, matrix, float4 col group); all W loads dwordx4,
// all x reads broadcast ds_read_b128.
__global__ __launch_bounds__(256) void gemm_lr(
        const float* __restrict__ x, const float* __restrict__ Wl,
        const float* __restrict__ bl, const float* __restrict__ Wr,
        const float* __restrict__ br, float* __restrict__ xl,
        float* __restrict__ xr) {
    __shared__ float4 xs[16 * 16];        // 16 rows x 16 float4 (=64 c), 4 KB
    const int tid  = threadIdx.x;
    const int r0   = blockIdx.x * 16;
    const int half = tid >> 7;            // row group 0/1
    const int q    = tid & 127;
    const int mat  = q >> 6;              // 0=Wl, 1=Wr
    const int col4 = q & 63;              // float4 column group 0..63
    const float* W  = mat ? Wr : Wl;
    const float* bv = mat ? br : bl;
    float*       o  = mat ? xr : xl;

    xs[tid] = ((const float4*)(x + (size_t)r0 * C_))[tid];
    __syncthreads();

    const float4 b4 = ((const float4*)bv)[col4];
    float4 acc[8];
    #pragma unroll
    for (int r = 0; r < 8; ++r) acc[r] = b4;

    const int rbase = half * 8;
    #pragma unroll 2
    for (int c4 = 0; c4 < 16; ++c4) {
        const float4 w0 = ((const float4*)(W + (size_t)(c4 * 4 + 0) * HC_))[col4];
        const float4 w1 = ((const float4*)(W + (size_t)(c4 * 4 + 1) * HC_))[col4];
        const float4 w2 = ((const float4*)(W + (size_t)(c4 * 4 + 2) * HC_))[col4];
        const float4 w3 = ((const float4*)(W + (size_t)(c4 * 4 + 3) * HC_))[col4];
        #pragma unroll
        for (int r = 0; r < 8; ++r) {
            const float4 xv = xs[(rbase + r) * 16 + c4];
            acc[r].x = fmaf(xv.x, w0.x, acc[r].x);
            acc[r].y = fmaf(xv.x, w0.y, acc[r].y);
            acc[r].z = fmaf(xv.x, w0.z, acc[r].z);
            acc[r].w = fmaf(xv.x, w0.w, acc[r].w);
            acc[r].x = fmaf(xv.y, w1.x, acc[r].x);
            acc[r].y = fmaf(xv.y, w1.y, acc[r].y);
            acc[r].z = fmaf(xv.y, w1.z, acc[r].z);
            acc[r].w = fmaf(xv.y, w1.w, acc[r].w);
            acc[r].x = fmaf(xv.z, w2.x, acc[r].x);
            acc[r].y = fmaf(xv.z, w2.y, acc[r].y);
            acc[r].z = fmaf(xv.z, w2.z, acc[r].z);
            acc[r].w = fmaf(xv.z, w2.w, acc[r].w);
            acc[r].x = fmaf(xv.w, w3.x, acc[r].x);
            acc[r].y = fmaf(xv.w, w3.y, acc[r].y);
            acc[r].z = fmaf(xv.w, w3.z, acc[r].z);
            acc[r].w = fmaf(xv.w, w3.w, acc[r].w);
        }
    }
    #pragma unroll
    for (int r = 0; r < 8; ++r)
        ((float4*)(o + (size_t)(r0 + rbase + r) * HC_))[col4] = acc[r];
}

// ---- CSR build
__global__ __launch_bounds__(256) void hist_kernel(
        const int* __restrict__ dst, int* __restrict__ count) {
    const int e = blockIdx.x * 256 + threadIdx.x;
    if (e < E_) atomicAdd(&count[dst[e]], 1);
}

__global__ __launch_bounds__(1024) void scan_kernel(
        const int* __restrict__ count, int* __restrict__ row_start) {
    __shared__ int part[1024];
    const int tid = threadIdx.x;
    const int base = tid * 10;
    int local[10];
    int s = 0;
    #pragma unroll
    for (int i = 0; i < 10; ++i) {
        const int idx = base + i;
        const int v = (idx < N_) ? count[idx] : 0;
        local[i] = s;
        s += v;
    }
    part[tid] = s;
    __syncthreads();
    for (int off = 1; off < 1024; off <<= 1) {
        const int v = (tid >= off) ? part[tid - off] : 0;
        __syncthreads();
        part[tid] += v;
        __syncthreads();
    }
    const int prefix = (tid > 0) ? part[tid - 1] : 0;
    #pragma unroll
    for (int i = 0; i < 10; ++i) {
        const int idx = base + i;
        if (idx < N_) row_start[idx] = prefix + local[i];
    }
    if (tid == 1023) row_start[N_] = part[1023];
}

__global__ __launch_bounds__(256) void scatter_kernel(
        const int* __restrict__ src, const int* __restrict__ dst,
        const int* __restrict__ row_start, int* __restrict__ cursor,
        int* __restrict__ perm_src) {
    const int e = blockIdx.x * 256 + threadIdx.x;
    if (e >= E_) return;
    const int d = dst[e];
    const int pos = row_start[d] + atomicAdd(&cursor[d], 1);
    perm_src[pos] = src[e];
}

// ---- Fused per-node attention: one 64-lane wave per (t,n), no LDS/barriers
__global__ __launch_bounds__(256) void node_agg(
        const float* __restrict__ xl, const float* __restrict__ xr,
        const float* __restrict__ att, const int* __restrict__ perm_src,
        const int* __restrict__ row_start, float* __restrict__ agg) {
    const int wid  = blockIdx.x * 4 + (threadIdx.x >> 6);   // t*N + n
    const int lane = threadIdx.x & 63;
    const int t = wid / N_, n = wid % N_;
    const int beg = row_start[n], end = row_start[n + 1];
    const float4 xi = ((const float4*)&xr[(size_t)wid * HC_])[lane];
    const float4 av = ((const float4*)att)[lane];
    const float* xlt = xl + (size_t)t * N_ * HC_;

    float m = -INFINITY, s = 0.f;
    float4 acc = make_float4(0.f, 0.f, 0.f, 0.f);

    for (int base = beg; base < end; base += 64) {
        const int cnt = min(64, end - base);
        const int myidx = (lane < cnt) ? perm_src[base + lane] : 0;
        // prefetch first row of chunk
        float4 xj = ((const float4*)&xlt[(size_t)__shfl(myidx, 0, 64) * HC_])[lane];
        for (int k = 0; k < cnt; ++k) {
            const float4 cur = xj;
            if (k + 1 < cnt) {
                const int sn = __shfl(myidx, k + 1, 64);
                xj = ((const float4*)&xlt[(size_t)sn * HC_])[lane];
            }
            // alpha: dot over this lane's 4 channels, reduce over 16-lane head
            float p =      lrelu(xi.x + cur.x) * av.x;
            p = fmaf(lrelu(xi.y + cur.y), av.y, p);
            p = fmaf(lrelu(xi.z + cur.z), av.z, p);
            p = fmaf(lrelu(xi.w + cur.w), av.w, p);
            p += __shfl_xor(p, 1, 64);
            p += __shfl_xor(p, 2, 64);
            p += __shfl_xor(p, 4, 64);
            p += __shfl_xor(p, 8, 64);
            // online softmax (uniform within each 16-lane head group)
            const float m_new = fmaxf(m, p);
            const float sc = __expf(m - m_new);
            const float w  = __expf(p - m_new);
            s = fmaf(s, sc, w);
            acc.x = fmaf(w, cur.x, acc.x * sc);
            acc.y = fmaf(w, cur.y, acc.y * sc);
            acc.z = fmaf(w, cur.z, acc.z * sc);
            acc.w = fmaf(w, cur.w, acc.w * sc);
            m = m_new;
        }
    }
    if (end > beg) {
        const float inv = 1.f / s;
        acc.x *= inv; acc.y *= inv; acc.z *= inv; acc.w *= inv;
    }
    ((float4*)&agg[(size_t)wid * HC_])[lane] = acc;
}

// ---- Pass E: relu(agg+bias) @ W_proj + b_proj + x -> LN -> relu
// 32 rows per block (4 waves x 8 rows); Wp read amortized
__global__ __launch_bounds__(256) void epilogue(
        const float* __restrict__ agg, const float* __restrict__ bias,
        const float* __restrict__ Wp, const float* __restrict__ bp,
        const float* __restrict__ x, const float* __restrict__ gamma,
        const float* __restrict__ beta, float* __restrict__ out) {
    __shared__ float sh[32 * HC_];       // 32 KB
    const int r0  = blockIdx.x * 32;
    const int tid = threadIdx.x;
    #pragma unroll
    for (int i = 0; i < 8; ++i) {
        const int slot = i * 256 + tid;          // float4 index
        const int r = slot >> 6, f4 = slot & 63;
        float4 v = ((const float4*)&agg[(size_t)(r0 + r) * HC_])[f4];
        const float4 b = ((const float4*)bias)[f4];
        v.x = fmaxf(v.x + b.x, 0.f); v.y = fmaxf(v.y + b.y, 0.f);
        v.z = fmaxf(v.z + b.z, 0.f); v.w = fmaxf(v.w + b.w, 0.f);
        ((float4*)sh)[slot] = v;
    }
    __syncthreads();
    const int wave = tid >> 6, o = tid & 63;
    const int rbase = wave * 8;                  // local row base
    const float bpo = bp[o];
    float acc[8];
    #pragma unroll
    for (int r = 0; r < 8; ++r)
        acc[r] = bpo + x[(size_t)(r0 + rbase + r) * C_ + o];
    for (int k = 0; k < HC_; k += 4) {
        const float w0 = Wp[(k + 0) * Co_ + o];
        const float w1 = Wp[(k + 1) * Co_ + o];
        const float w2 = Wp[(k + 2) * Co_ + o];
        const float w3 = Wp[(k + 3) * Co_ + o];
        #pragma unroll
        for (int r = 0; r < 8; ++r) {
            const float4 s4 = ((const float4*)&sh[(rbase + r) * HC_])[k >> 2];
            acc[r] = fmaf(s4.x, w0, acc[r]);
            acc[r] = fmaf(s4.y, w1, acc[r]);
            acc[r] = fmaf(s4.z, w2, acc[r]);
            acc[r] = fmaf(s4.w, w3, acc[r]);
        }
    }
    const float go = gamma[o], bo = beta[o];
    #pragma unroll
    for (int r = 0; r < 8; ++r) {
        float s1 = acc[r];
        #pragma unroll
        for (int off = 1; off < 64; off <<= 1) s1 += __shfl_xor(s1, off, 64);
        const float mu = s1 * (1.f / 64.f);
        const float dv = acc[r] - mu;
        float s2 = dv * dv;
        #pragma unroll
        for (int off = 1; off < 64; off <<= 1) s2 += __shfl_xor(s2, off, 64);
        const float var = s2 * (1.f / 64.f);
        const float y = dv * rsqrtf(var + LN_EPS) * go + bo;
        out[(size_t)(r0 + rbase + r) * C_ + o] = fmaxf(y, 0.f);
    }
}

extern "C" void kernel_launch(void* const* d_in, const int* in_sizes, int n_in,
                              void* d_out, int out_size, void* d_ws, size_t ws_size,
                              hipStream_t stream) {
    const float* x    = (const float*)d_in[0];
    const int*   ei   = (const int*)  d_in[1];
    const float* Wl   = (const float*)d_in[2];
    const float* bl   = (const float*)d_in[3];
    const float* Wr   = (const float*)d_in[4];
    const float* br   = (const float*)d_in[5];
    const float* att  = (const float*)d_in[6];
    const float* bias = (const float*)d_in[7];
    const float* Wp   = (const float*)d_in[8];
    const float* bp   = (const float*)d_in[9];
    const float* gam  = (const float*)d_in[10];
    const float* bet  = (const float*)d_in[11];
    const int* src = ei;            // edge_index[0]
    const int* dst = ei + E_;       // edge_index[1]

    float* ws = (float*)d_ws;
    float* xl  = ws;                                   // T*N*HC
    float* xr  = xl + (size_t)T_ * N_ * HC_;
    float* agg = xr + (size_t)T_ * N_ * HC_;           // T*N*HC
    int* row_start = (int*)(agg + (size_t)T_ * N_ * HC_);  // N+1
    int* count     = row_start + (N_ + 1);                 // N
    int* cursor    = count + N_;                           // N
    int* perm_src  = cursor + N_;                          // E

    hipMemsetAsync(count, 0, 2 * N_ * sizeof(int), stream);

    hist_kernel   <<<(E_ + 255) / 256, 256, 0, stream>>>(dst, count);
    scan_kernel   <<<1, 1024, 0, stream>>>(count, row_start);
    scatter_kernel<<<(E_ + 255) / 256, 256, 0, stream>>>(src, dst, row_start,
                                                         cursor, perm_src);
    gemm_lr <<<T_ * N_ / 16, 256, 0, stream>>>(x, Wl, bl, Wr, br, xl, xr);
    node_agg<<<T_ * N_ / 4,  256, 0, stream>>>(xl, xr, att, perm_src,
                                               row_start, agg);
    epilogue<<<T_ * N_ / 32, 256, 0, stream>>>(agg, bias, Wp, bp, x, gam, bet,
                                               (float*)d_out);
}